// Round 1
// baseline (100.287 us; speedup 1.0000x reference)
//
#include <hip/hip_runtime.h>
#include <math.h>

// Problem constants
#define T_COLS 147456   // N_R*3*N_D*C = 1024*3*16*3
#define BS 8

// ws layout (float offsets), all fully written before read each call
#define OFF_ME      0                              // 256*8
#define OFF_THETA   2048                           // 8*147456
#define OFF_MULP    (OFF_THETA + BS*T_COLS)        // 8*3*1024*16
#define OFF_ADDSUM  (OFF_MULP + 8*3*1024*16)       // 8*3*1024
#define OFF_ROWSTAT (OFF_ADDSUM + 8*3*1024)        // 384*2
#define OFF_Q       (OFF_ROWSTAT + 768)            // 8*3*1024

// K1: mean_emb[k][b] = mean over 64 spatial of patch_emb[b,:,:,k] (transposed for K2's LDS)
__global__ void k1_mean(const float* __restrict__ pe, float* __restrict__ me) {
    int b = blockIdx.x;          // 8
    int k = threadIdx.x;         // 256
    const float* p = pe + (size_t)b * 64 * 256 + k;
    float s = 0.f;
#pragma unroll 8
    for (int i = 0; i < 64; i++) s += p[i * 256];
    me[k * 8 + b] = s * (1.f / 64.f);
}

// K2: theta[b][t] = sum_k me[b][k]*w[k][t] + bias[t]. 2 columns/thread (float2).
// HBM-bound: streams 151 MB of w once.
__global__ __launch_bounds__(256) void k2_gemm(const float* __restrict__ w,
                                               const float* __restrict__ bt,
                                               const float* __restrict__ me,
                                               float* __restrict__ theta) {
    __shared__ __align__(16) float lme[2048];   // [k][b]
    int tid = threadIdx.x;
#pragma unroll
    for (int i = 0; i < 8; i++) lme[tid + i * 256] = me[tid + i * 256];
    __syncthreads();

    int t = (blockIdx.x * 256 + tid) * 2;
    float2 acc[8];
#pragma unroll
    for (int b = 0; b < 8; b++) { acc[b].x = 0.f; acc[b].y = 0.f; }

#pragma unroll 8
    for (int k = 0; k < 256; k++) {
        float2 wv = *reinterpret_cast<const float2*>(&w[(size_t)k * T_COLS + t]);
        const float4* m4 = reinterpret_cast<const float4*>(&lme[k * 8]);
        float4 m0 = m4[0], m1 = m4[1];
        acc[0].x += m0.x * wv.x; acc[0].y += m0.x * wv.y;
        acc[1].x += m0.y * wv.x; acc[1].y += m0.y * wv.y;
        acc[2].x += m0.z * wv.x; acc[2].y += m0.z * wv.y;
        acc[3].x += m0.w * wv.x; acc[3].y += m0.w * wv.y;
        acc[4].x += m1.x * wv.x; acc[4].y += m1.x * wv.y;
        acc[5].x += m1.y * wv.x; acc[5].y += m1.y * wv.y;
        acc[6].x += m1.z * wv.x; acc[6].y += m1.z * wv.y;
        acc[7].x += m1.w * wv.x; acc[7].y += m1.w * wv.y;
    }
    float2 bv = *reinterpret_cast<const float2*>(&bt[t]);
#pragma unroll
    for (int b = 0; b < 8; b++) {
        float2 o; o.x = acc[b].x + bv.x; o.y = acc[b].y + bv.y;
        *reinterpret_cast<float2*>(&theta[(size_t)b * T_COLS + t]) = o;
    }
}

// K3a: per-(b,d,c) softmax stats over the 1024 range patches: max and 1/sum(exp)
__global__ void k3a_rowstat(const float* __restrict__ theta, float* __restrict__ rs) {
    int row = blockIdx.x;                 // b*48 + d*3 + c, 384 rows
    int b = row / 48, dc = row % 48;
    const float* base = theta + (size_t)b * T_COLS + 2048 * 48 + dc;
    int tid = threadIdx.x;
    __shared__ float red[256];

    float v[4];
    float m = -1e30f;
#pragma unroll
    for (int i = 0; i < 4; i++) {
        v[i] = base[(size_t)(tid + i * 256) * 48];
        m = fmaxf(m, v[i]);
    }
    red[tid] = m; __syncthreads();
    for (int s = 128; s > 0; s >>= 1) {
        if (tid < s) red[tid] = fmaxf(red[tid], red[tid + s]);
        __syncthreads();
    }
    m = red[0]; __syncthreads();

    float sum = 0.f;
#pragma unroll
    for (int i = 0; i < 4; i++) sum += __expf(v[i] - m);
    red[tid] = sum; __syncthreads();
    for (int s = 128; s > 0; s >>= 1) {
        if (tid < s) red[tid] += red[tid + s];
        __syncthreads();
    }
    if (tid == 0) { rs[row * 2] = m; rs[row * 2 + 1] = 1.f / red[0]; }
}

// K3b: mulp[b,c,r,d] = tanh(mul)*softmax(mix); addsum[b,c,r] = sum_d tanh(add)*softmax(mix)
__global__ void k3b_post(const float* __restrict__ theta, const float* __restrict__ rs,
                         float* __restrict__ mulp, float* __restrict__ addsum) {
    int g = blockIdx.x * 256 + threadIdx.x;     // 24576 = 8*3*1024
    int bc = g >> 10;
    int r = g & 1023;
    int b = bc / 3, c = bc % 3;
    const float* tb = theta + (size_t)b * T_COLS;

    float out[16];
    float asum = 0.f;
#pragma unroll
    for (int d = 0; d < 16; d++) {
        int col = d * 3 + c;
        float mx = tb[(size_t)(2048 + r) * 48 + col];
        float mu = tb[(size_t)r * 48 + col];
        float ad = tb[(size_t)(1024 + r) * 48 + col];
        int row = b * 48 + d * 3 + c;
        float sm = __expf(mx - rs[row * 2]) * rs[row * 2 + 1];
        out[d] = tanhf(mu) * sm;
        asum += tanhf(ad) * sm;
    }
    float4* mp = reinterpret_cast<float4*>(&mulp[(size_t)g * 16]);
    mp[0] = make_float4(out[0], out[1], out[2], out[3]);
    mp[1] = make_float4(out[4], out[5], out[6], out[7]);
    mp[2] = make_float4(out[8], out[9], out[10], out[11]);
    mp[3] = make_float4(out[12], out[13], out[14], out[15]);
    addsum[g] = asum;
}

// K4: per (b,c): A[16][16], s[16]; iterate p_n = A p + s 8 times; q[r] = addsum[r] + mulp[r,:]·p8
__global__ __launch_bounds__(256) void k4_Apq(const float* __restrict__ mulp,
                                              const float* __restrict__ addsum,
                                              float* __restrict__ q) {
    int bc = blockIdx.x;    // 24
    int tid = threadIdx.x;
    __shared__ float A[256];
    __shared__ float sv[16];
    const float* mp = mulp + (size_t)bc * 1024 * 16;
    const float* as = addsum + (size_t)bc * 1024;

    {   // A[dd][d] = mean over the 64 range patches inside domain dd of mulp[r][d]
        int dd = tid >> 4, d = tid & 15;
        int di = dd >> 2, dj = dd & 3;
        float sum = 0.f;
        for (int a = 0; a < 8; a++)
#pragma unroll
            for (int e = 0; e < 8; e++) {
                int r = (di * 8 + a) * 32 + dj * 8 + e;
                sum += mp[(size_t)r * 16 + d];
            }
        A[tid] = sum * (1.f / 64.f);
    }
    if (tid < 16) {
        int di = tid >> 2, dj = tid & 3;
        float sum = 0.f;
        for (int a = 0; a < 8; a++)
#pragma unroll
            for (int e = 0; e < 8; e++) sum += as[(di * 8 + a) * 32 + dj * 8 + e];
        sv[tid] = sum * (1.f / 64.f);
    }
    __syncthreads();

    // p_8 via 8 affine steps (redundant per thread, trivial)
    float p[16];
#pragma unroll
    for (int d = 0; d < 16; d++) p[d] = 0.f;
    for (int it = 0; it < 8; it++) {
        float pn[16];
#pragma unroll
        for (int d2 = 0; d2 < 16; d2++) {
            float x = sv[d2];
#pragma unroll
            for (int d = 0; d < 16; d++) x += A[d2 * 16 + d] * p[d];
            pn[d2] = x;
        }
#pragma unroll
        for (int d = 0; d < 16; d++) p[d] = pn[d];
    }

#pragma unroll
    for (int i = 0; i < 4; i++) {
        int r = tid + i * 256;
        float x = as[r];
        const float* row = &mp[(size_t)r * 16];
#pragma unroll
        for (int d = 0; d < 16; d++) x += row[d] * p[d];
        q[(size_t)bc * 1024 + r] = x;
    }
}

// K5: final image. out[b,i,j,c] = addsum[r] + sum_dd mulp[b,c,r,dd]*q[b,c,r2(dd,h,w)]
__global__ void k5_final(const float* __restrict__ mulp, const float* __restrict__ addsum,
                         const float* __restrict__ q, float* __restrict__ out) {
    int g = blockIdx.x * 256 + threadIdx.x;     // 1572864
    int c = g % 3;
    int j = (g / 3) & 255;
    int i = (g / 768) & 255;
    int b = g / 196608;
    int ri = i >> 3, h = i & 7, rj = j >> 3, w = j & 7;
    int r = ri * 32 + rj;
    int bc = b * 3 + c;
    const float* qb = q + (size_t)bc * 1024;
    const float* mrow = mulp + ((size_t)bc * 1024 + r) * 16;

    float acc = addsum[(size_t)bc * 1024 + r];
#pragma unroll
    for (int di = 0; di < 4; di++) {
        int r2 = (di * 8 + h) * 32 + w;
#pragma unroll
        for (int dj = 0; dj < 4; dj++) {
            acc += mrow[di * 4 + dj] * qb[r2 + dj * 8];
        }
    }
    out[g] = acc;
}

extern "C" void kernel_launch(void* const* d_in, const int* in_sizes, int n_in,
                              void* d_out, int out_size, void* d_ws, size_t ws_size,
                              hipStream_t stream) {
    const float* pe = (const float*)d_in[0];   // (8,8,8,256)
    const float* w  = (const float*)d_in[1];   // (256,147456)
    const float* bt = (const float*)d_in[2];   // (147456,)
    float* ws = (float*)d_ws;

    float* me     = ws + OFF_ME;
    float* theta  = ws + OFF_THETA;
    float* mulp   = ws + OFF_MULP;
    float* addsum = ws + OFF_ADDSUM;
    float* rs     = ws + OFF_ROWSTAT;
    float* q      = ws + OFF_Q;
    float* out = (float*)d_out;

    k1_mean<<<8, 256, 0, stream>>>(pe, me);
    k2_gemm<<<T_COLS / 512, 256, 0, stream>>>(w, bt, me, theta);   // 288 blocks
    k3a_rowstat<<<384, 256, 0, stream>>>(theta, rs);
    k3b_post<<<96, 256, 0, stream>>>(theta, rs, mulp, addsum);
    k4_Apq<<<24, 256, 0, stream>>>(mulp, addsum, q);
    k5_final<<<6144, 256, 0, stream>>>(mulp, addsum, q, out);
}